// Round 9
// baseline (455.876 us; speedup 1.0000x reference)
//
#include <hip/hip_runtime.h>
#include <math.h>

#define BATCH 16
#define TA 2048
#define TV 1024
#define TT 1536
#define DIM 256
#define FD 512

typedef unsigned short u16;
typedef unsigned int u32;
typedef short bf16x8 __attribute__((ext_vector_type(8)));
typedef float f32x4 __attribute__((ext_vector_type(4)));

__device__ __forceinline__ float bf2f(u16 u) {
  union { u32 i; float f; } v; v.i = ((u32)u) << 16; return v.f;
}
__device__ __forceinline__ u16 f2bf(float f) {
  union { float f; u32 i; } v; v.f = f;
  return (u16)((v.i + 0x7fffu + ((v.i >> 16) & 1u)) >> 16);  // RNE
}
__device__ __forceinline__ float gelu_f(float x) {
  return 0.5f * x * (1.0f + erff(x * 0.70710678118654752440f));
}
// async global->LDS, 16B per lane. LDS dest = wave-uniform base + lane*16.
__device__ __forceinline__ void async16(const u16* g, u16* l) {
  __builtin_amdgcn_global_load_lds((const __attribute__((address_space(1))) void*)g,
                                   (__attribute__((address_space(3))) void*)l, 16, 0, 0);
}

// ---- weight prep: fp32 -> bf16 (+ zeroing the nsq accumulators, fused).
// Conv weights permuted to K-ordered async16-ready chunks:
//   W[kk][unit][8] with kk = tap*8 + c0/32, unit = (o>>4)*64 + q*16 + (o&15),
//   elem j: c = (kk&7)*32 + q*8 + j. Chunk kk = 8 KB contiguous.
__global__ __launch_bounds__(256) void k_prep(
    const float* __restrict__ a3w, const float* __restrict__ a5w,
    const float* __restrict__ v3w, const float* __restrict__ v5w,
    const float* __restrict__ pw,
    u16* __restrict__ w3a, u16* __restrict__ w5a,
    u16* __restrict__ w3v, u16* __restrict__ w5v, u16* __restrict__ wp,
    float* __restrict__ nz) {
  int idx = blockIdx.x * 256 + threadIdx.x;
  if (idx < 524288) {
    int e, ktaps;
    const float* src;
    u16* dst;
    if (idx < 98304)       { e = idx;          ktaps = 3; src = a3w; dst = w3a; }
    else if (idx < 262144) { e = idx - 98304;  ktaps = 5; src = a5w; dst = w5a; }
    else if (idx < 360448) { e = idx - 262144; ktaps = 3; src = v3w; dst = w3v; }
    else                   { e = idx - 360448; ktaps = 5; src = v5w; dst = w5v; }
    int kk = e >> 12, r = e & 4095;
    int j = r & 7, unit = r >> 3;
    int fb = unit >> 6, rem = unit & 63;
    int q = rem >> 4, colp = rem & 15;
    int o = fb * 16 + colp;
    int tap = kk >> 3;
    int c = (kk & 7) * 32 + q * 8 + j;
    dst[e] = f2bf(src[(o * 256 + c) * ktaps + tap]);
  } else if (idx < 786432) {               // proj [512][512] straight copy
    int t = idx - 524288;
    wp[t] = f2bf(pw[t]);
  } else if (idx < 835584) {               // zero naq/nvq (adjacent, 49152 f32)
    nz[idx - 786432] = 0.f;
  }
}

// ---------------- linear interp to T=1536, output bf16 [B][T][256] ----------
__global__ __launch_bounds__(256) void k_interp(const float* __restrict__ in,
                                                u16* __restrict__ out,
                                                int t_in, float scale) {
  int b = blockIdx.y;
  int i = blockIdx.x * 256 + threadIdx.x;   // [0, TT*32)
  int t = i >> 5, dg = i & 31;              // dg: group of 8 dims
  float src = ((float)t + 0.5f) * scale - 0.5f;
  src = fmaxf(src, 0.0f);
  int i0 = (int)floorf(src);
  if (i0 > t_in - 1) i0 = t_in - 1;
  int i1 = i0 + 1; if (i1 > t_in - 1) i1 = t_in - 1;
  float w = src - (float)i0;
  float om = 1.0f - w;
  const float4* p0 = (const float4*)(in + ((size_t)(b * t_in + i0)) * DIM + dg * 8);
  const float4* p1 = (const float4*)(in + ((size_t)(b * t_in + i1)) * DIM + dg * 8);
  float4 x0a = p0[0], x0b = p0[1], x1a = p1[0], x1b = p1[1];
  u16 r[8];
  r[0] = f2bf(x0a.x * om + x1a.x * w); r[1] = f2bf(x0a.y * om + x1a.y * w);
  r[2] = f2bf(x0a.z * om + x1a.z * w); r[3] = f2bf(x0a.w * om + x1a.w * w);
  r[4] = f2bf(x0b.x * om + x1b.x * w); r[5] = f2bf(x0b.y * om + x1b.y * w);
  r[6] = f2bf(x0b.z * om + x1b.z * w); r[7] = f2bf(x0b.w * om + x1b.w * w);
  u32 w0 = (u32)r[0] | ((u32)r[1] << 16), w1 = (u32)r[2] | ((u32)r[3] << 16);
  u32 w2 = (u32)r[4] | ((u32)r[5] << 16), w3 = (u32)r[6] | ((u32)r[7] << 16);
  *(uint4*)(out + ((size_t)(b * TT + t)) * DIM + dg * 8) = make_uint4(w0, w1, w2, w3);
}

// ---------------- conv GEMM, fully unrolled, channel-split -----------------
// TAPS=3 -> output channels [0,128), TAPS=5 -> [128,256).
// Per block: 64 t-rows x 128 channels. z selects audio/video.
// Wave w owns channels [w*32, w*32+32) for all 64 rows.
// nsq accumulated atomically (pre-zeroed).
template <int TAPS>
__global__ __launch_bounds__(256) void k_convN(
    const u16* __restrict__ xa, const u16* __restrict__ xv,
    const u16* __restrict__ Wa, const u16* __restrict__ Wv,
    const float* __restrict__ ba, const float* __restrict__ bv,
    u16* __restrict__ outMa, u16* __restrict__ outMv,
    u16* __restrict__ outTa, u16* __restrict__ outTv,
    float* __restrict__ nsqa, float* __restrict__ nsqv) {
  constexpr int S = TAPS * 8;
  constexpr int OFF = (TAPS == 3) ? 1 : 2;
  constexpr int CHB = (TAPS == 3) ? 0 : 128;
  __shared__ __align__(16) u16 xs[68 * 264];   // input rows t0-2..t0+65; tb overlays
  __shared__ __align__(16) u16 Bs[2 * 4096];   // weight chunk double buffer
  u16* tb = xs;                                // [128][72] transpose buffer (epilogue)
  int b = blockIdx.y, t0 = blockIdx.x * 64;
  int isv = blockIdx.z;
  const u16* xin = isv ? xv : xa;
  const u16* W   = isv ? Wv : Wa;
  const float* bias = isv ? bv : ba;
  u16* outM  = isv ? outMv : outMa;
  u16* outT  = isv ? outTv : outTa;
  float* nsq = isv ? nsqv : nsqa;
  int tid = threadIdx.x, wave = tid >> 6, lane = tid & 63;
  int col = lane & 15, quad = lane >> 4;

  // stage 68 input rows (zeros outside [0,T))
  for (int i = tid; i < 68 * 32; i += 256) {
    int row = i >> 5, un = i & 31;
    int t = t0 + row - 2;
    uint4 val = make_uint4(0, 0, 0, 0);
    if (t >= 0 && t < TT) val = *(const uint4*)(xin + ((size_t)(b * TT + t)) * DIM + un * 8);
    *(uint4*)(xs + row * 264 + un * 8) = val;
  }
  // prefetch chunk 0 into buf 0 (each wave stages 1024 elems = 2 x 16B/lane)
  const u16* Wb = W + wave * 1024 + lane * 8;
  u16* BsW = Bs + wave * 1024;
  async16(Wb, BsW);
  async16(Wb + 512, BsW + 512);

  f32x4 acc[4][2];
  f32x4 zz = {0.f, 0.f, 0.f, 0.f};
#pragma unroll
  for (int rt = 0; rt < 4; rt++) { acc[rt][0] = zz; acc[rt][1] = zz; }

  const u16* afp = xs + (col + 2) * 264 + quad * 8;
  const u16* bfp = Bs + wave * 1024 + quad * 128 + col * 8;

#pragma unroll
  for (int s = 0; s < S; s++) {
    __syncthreads();                 // chunk s staged; prev reads of other buf done
    if (s + 1 < S) {
      const u16* src = Wb + (size_t)(s + 1) * 4096;
      u16* dst = Bs + ((s + 1) & 1) * 4096 + wave * 1024;
      async16(src, dst);
      async16(src + 512, dst + 512);
    }
    int shift = (s >> 3) - OFF;      // compile-time after unroll
    int c0 = (s & 7) * 32;
    bf16x8 af[4];
#pragma unroll
    for (int rt = 0; rt < 4; rt++)
      af[rt] = *(const bf16x8*)(afp + (rt * 16 + shift) * 264 + c0);
    bf16x8 bf0 = *(const bf16x8*)(bfp + (s & 1) * 4096);
    bf16x8 bf1 = *(const bf16x8*)(bfp + (s & 1) * 4096 + 512);
#pragma unroll
    for (int rt = 0; rt < 4; rt++) {
      acc[rt][0] = __builtin_amdgcn_mfma_f32_16x16x32_bf16(af[rt], bf0, acc[rt][0], 0, 0, 0);
      acc[rt][1] = __builtin_amdgcn_mfma_f32_16x16x32_bf16(af[rt], bf1, acc[rt][1], 0, 0, 0);
    }
  }
  __syncthreads();                   // xs reads done; safe to overlay tb

  // epilogue: bias + gelu + per-row sumsq (32 ch of this wave) + tb + outM
  float bia0 = bias[wave * 32 + col];
  float bia1 = bias[wave * 32 + 16 + col];
  float ss[4][4];
#pragma unroll
  for (int rt = 0; rt < 4; rt++)
#pragma unroll
    for (int r = 0; r < 4; r++) ss[rt][r] = 0.f;
#pragma unroll
  for (int rt = 0; rt < 4; rt++)
#pragma unroll
    for (int h = 0; h < 2; h++) {
      float bia = h ? bia1 : bia0;
      int chL = wave * 32 + h * 16 + col;
#pragma unroll
      for (int r = 0; r < 4; r++) {
        float g = gelu_f(acc[rt][h][r] + bia);
        ss[rt][r] += g * g;
        int trow = rt * 16 + quad * 4 + r;
        u16 gb = f2bf(g);
        tb[chL * 72 + trow] = gb;
        outM[((size_t)(b * TT + t0 + trow)) * DIM + CHB + chL] = gb;
      }
    }
#pragma unroll
  for (int rt = 0; rt < 4; rt++)
#pragma unroll
    for (int r = 0; r < 4; r++) {
      float v = ss[rt][r];
      v += __shfl_xor(v, 1, 64); v += __shfl_xor(v, 2, 64);
      v += __shfl_xor(v, 4, 64); v += __shfl_xor(v, 8, 64);
      if (col == 0)
        atomicAdd(&nsq[b * TT + t0 + rt * 16 + quad * 4 + r], v);
    }
  __syncthreads();
  // outT: 2 threads per channel write 32 contiguous t each
  {
    int ch = tid >> 1, half = tid & 1;
    uint4* dst = (uint4*)(outT + ((size_t)(b * 256 + CHB + ch)) * TT + t0 + half * 32);
#pragma unroll
    for (int i = 0; i < 4; i++)
      dst[i] = *(const uint4*)(tb + ch * 72 + half * 32 + i * 8);
  }
}

// ---- fused flash cross-attention (r6 schedule, 96-row/6-wave blocks).
// 512 blocks, 384 thr (6 waves: mg 0..2 x ng 0..1), 96 Q-rows/block,
// 24 KV-steps of 64 rows, LDS 76.75 KB -> exactly 2 blocks/CU, grid
// 512 = 2 x 256: ALL blocks resident, no tail (r6's 768-block grid ran a
// 256-block tail third at 1/CU). 12 waves/CU = 3/SIMD.
// Role-split staging keeps per-wave vmcnt counts exact:
//   waves 0-3: 8 sKV units each at P2 (+2 rv loads first)
//   waves 4-5: 16 sKT units each at P3 (+2 rv loads at P2)
// Per step:
//   P1 sim+exp            B1 vmcnt(0)+lgkm+bar  (sKT(t) lands under sim)
//   P2 rv + [w<4]sKV(t+1), PV   B2 lgkm+bar
//   P3 [w>=4]sKT(t+1)     W  w<4: vmcnt(0) (rv+sKV drain);
//                            w>=4: vmcnt(16) (retires exactly rv; 16 sKT fly on)
// E = exp(cossim*sRa*sRv) bounded => no running max.
// r7 ERRATA kept: scalar f2bf epilogue (packed cvt_pk stores = bank conflicts).
__global__ __launch_bounds__(384, 3) void k_flash(
    const u16* __restrict__ aM, const u16* __restrict__ vM,
    const u16* __restrict__ aMT, const u16* __restrict__ vMT,
    const float* __restrict__ naq, const float* __restrict__ nvq,
    const u16* __restrict__ a_itp, const u16* __restrict__ v_itp,
    u16* __restrict__ fused) {
  __shared__ __align__(16) u16 sKV[8 * 64 * 32];    // sim B  [kt][64][32]
  __shared__ __align__(16) u16 sKT[2 * 256 * 32];   // PV  B  [kn][256][32]
  __shared__ __align__(16) u16 sE[3 * 32 * 64];     // E      [mg][32][64]
  __shared__ float sDen[2][96];

  // XCD-chunked decode: 512 blocks = 16 m-tiles x 32 (b,z) groups;
  // 4 groups per XCD, 16 blocks of one group on one XCD L2.
  int wgid = blockIdx.x;                 // [0, 512)
  int xcd = wgid & 7, slot = wgid >> 3;  // slot in [0,64)
  int g = xcd + 8 * (slot >> 4);         // group (b,z) in [0,32)
  int m0 = (slot & 15) * 96;
  int b = g & 15, z = g >> 4;
  const u16* Q    = z ? vM : aM;
  const u16* KV   = z ? aM : vM;
  const u16* KVT  = z ? aMT : vMT;
  const float* nq = z ? nvq : naq;
  const float* nk = z ? naq : nvq;
  const u16* itp  = z ? v_itp : a_itp;
  int dstoff = z ? 256 : 0;

  int tid = threadIdx.x, w = tid >> 6, lane = tid & 63;
  int mg = w >> 1, ng = w & 1;              // mg 0..2, ng 0..1
  int col = lane & 15, quad = lane >> 4;
  int li = lane >> 2;                       // staging row within 16
  int sq = (lane & 3) ^ ((lane >> 3) & 3);  // pre-swizzled global k-slot

  const u16* KVb = KV + ((size_t)b * TT) * DIM;
  const u16* KTb = KVT + ((size_t)b * 256) * TT;
  const float* nkB = nk + (size_t)b * TT;

  // waves 0-3: 8 sKV units (kt = w*2+kk, rows i*16+li, dims kt*32+sq*8)
  auto stageKV = [&](int n0s) {
#pragma unroll
    for (int kk = 0; kk < 2; kk++) {
      int kt = w * 2 + kk;
#pragma unroll
      for (int i = 0; i < 4; i++)
        async16(KVb + (size_t)(n0s + i * 16 + li) * DIM + kt * 32 + sq * 8,
                sKV + kt * 2048 + i * 512);
    }
  };
  // waves 4-5: 16 sKT units (kn = w-4; d-rows i*16+li, n-slot kn*32+sq*8)
  auto stageKT = [&](int n0s) {
    int kn = w - 4;
#pragma unroll
    for (int i = 0; i < 16; i++)
      async16(KTb + (size_t)(i * 16 + li) * TT + n0s + kn * 32 + sq * 8,
              sKT + kn * 8192 + i * 512);
  };

  // Q fragments in registers: rows m0+mg*32+mt*16+col, k = kt*32+quad*8
  bf16x8 qf[2][8];
  const u16* Qb = Q + ((size_t)(b * TT + m0 + mg * 32)) * DIM;
#pragma unroll
  for (int mt = 0; mt < 2; mt++)
#pragma unroll
    for (int kt = 0; kt < 8; kt++)
      qf[mt][kt] = *(const bf16x8*)(Qb + (size_t)(mt * 16 + col) * DIM + kt * 32 + quad * 8);

  // inverse norms for this lane's 8 accumulator rows
  float sra[2][4];
#pragma unroll
  for (int mt = 0; mt < 2; mt++)
#pragma unroll
    for (int r = 0; r < 4; r++)
      sra[mt][r] = 1.0f / fmaxf(
          sqrtf(nq[(size_t)b * TT + m0 + mg * 32 + mt * 16 + quad * 4 + r]), 1e-12f);

  // per-lane K-norm columns (2 per step), step-0 raw values
  int c0 = ng * 32 + col, c1 = ng * 32 + 16 + col;
  float rvRaw0 = nkB[c0], rvRaw1 = nkB[c1];

  f32x4 acc[2][8];                       // PV accumulators [mt][dt]
  f32x4 zz = {0.f, 0.f, 0.f, 0.f};
#pragma unroll
  for (int mt = 0; mt < 2; mt++)
#pragma unroll
    for (int dt = 0; dt < 8; dt++) acc[mt][dt] = zz;
  float den[2][4];
#pragma unroll
  for (int mt = 0; mt < 2; mt++)
#pragma unroll
    for (int r = 0; r < 4; r++) den[mt][r] = 0.f;

  // prologue: stage step 0 by role, drain
  if (w < 4) stageKV(0); else stageKT(0);
  __syncthreads();

  for (int t = 0; t < 24; t++) {
    int n0 = t * 64;
    // ---- P1: sim (reads sKV only) + exp/sE
    f32x4 sc[2][2];
    sc[0][0] = zz; sc[0][1] = zz; sc[1][0] = zz; sc[1][1] = zz;
#pragma unroll
    for (int kt = 0; kt < 8; kt++)
#pragma unroll
      for (int nt = 0; nt < 2; nt++) {
        int row = ng * 32 + nt * 16 + col;
        bf16x8 bf = *(const bf16x8*)(sKV + kt * 2048 + row * 32 +
                                     ((quad ^ ((row >> 1) & 3)) << 3));
        sc[0][nt] = __builtin_amdgcn_mfma_f32_16x16x32_bf16(qf[0][kt], bf, sc[0][nt], 0, 0, 0);
        sc[1][nt] = __builtin_amdgcn_mfma_f32_16x16x32_bf16(qf[1][kt], bf, sc[1][nt], 0, 0, 0);
      }
    float rvi[2];
    rvi[0] = 1.0f / fmaxf(sqrtf(rvRaw0), 1e-12f);
    rvi[1] = 1.0f / fmaxf(sqrtf(rvRaw1), 1e-12f);
#pragma unroll
    for (int mt = 0; mt < 2; mt++)
#pragma unroll
      for (int nt = 0; nt < 2; nt++) {
        int c = ng * 32 + nt * 16 + col;
        float rv = rvi[nt];
#pragma unroll
        for (int r = 0; r < 4; r++) {
          float e = __expf(sc[mt][nt][r] * sra[mt][r] * rv);
          den[mt][r] += e;
          int row = mt * 16 + quad * 4 + r;
          sE[mg * 2048 + row * 64 + (((c >> 3) ^ ((row >> 1) & 7)) << 3) + (c & 7)] =
              f2bf(e);
        }
      }

    // ---- B1: sKT(t) landed + sE visible + all sKV reads done
    __builtin_amdgcn_sched_barrier(0);
    asm volatile("s_waitcnt vmcnt(0) lgkmcnt(0)" ::: "memory");
    __builtin_amdgcn_s_barrier();
    __builtin_amdgcn_sched_barrier(0);

    // ---- P2: rv loads (all waves) + [w<4] sKV(t+1); then PV (reads sE, sKT)
    int nn = (t < 23) ? (n0 + 64) : 0;
    float rvA = nkB[nn + c0], rvB = nkB[nn + c1];
    if (t < 23 && w < 4) stageKV(n0 + 64);
#pragma unroll
    for (int kn = 0; kn < 2; kn++) {
      bf16x8 ea0, ea1;
      {
        int row = col;                   // mt = 0
        ea0 = *(const bf16x8*)(sE + mg * 2048 + row * 64 +
                               (((kn * 4 + quad) ^ ((row >> 1) & 7)) << 3));
        row = 16 + col;                  // mt = 1
        ea1 = *(const bf16x8*)(sE + mg * 2048 + row * 64 +
                               (((kn * 4 + quad) ^ ((row >> 1) & 7)) << 3));
      }
#pragma unroll
      for (int dt = 0; dt < 8; dt++) {
        int drow = ng * 128 + dt * 16 + col;
        bf16x8 bf = *(const bf16x8*)(sKT + kn * 8192 + drow * 32 +
                                     ((quad ^ ((drow >> 1) & 3)) << 3));
        acc[0][dt] = __builtin_amdgcn_mfma_f32_16x16x32_bf16(ea0, bf, acc[0][dt], 0, 0, 0);
        acc[1][dt] = __builtin_amdgcn_mfma_f32_16x16x32_bf16(ea1, bf, acc[1][dt], 0, 0, 0);
      }
    }

    // ---- B2: all sKT(t)/sE reads done
    __builtin_amdgcn_sched_barrier(0);
    asm volatile("s_waitcnt lgkmcnt(0)" ::: "memory");
    __builtin_amdgcn_s_barrier();
    __builtin_amdgcn_sched_barrier(0);

    // ---- P3: [w>=4] issue sKT(t+1); W: role-split counted wait
    if (t < 23 && w >= 4) stageKT(n0 + 64);
    __builtin_amdgcn_sched_barrier(0);
    if (w < 4) {
      // drains rv + sKV(t+1) (needed next P1); nothing else outstanding
      asm volatile("s_waitcnt vmcnt(0) lgkmcnt(0)" ::: "memory");
    } else {
      // retires exactly the 2 rv loads; 16 sKT(t+1) stay in flight
      asm volatile("s_waitcnt vmcnt(16) lgkmcnt(0)" ::: "memory");
    }
    __builtin_amdgcn_s_barrier();
    __builtin_amdgcn_sched_barrier(0);

    rvRaw0 = rvA; rvRaw1 = rvB;
  }

  // den: butterfly over 16 cols, then combine the two ng waves via LDS
#pragma unroll
  for (int mt = 0; mt < 2; mt++)
#pragma unroll
    for (int r = 0; r < 4; r++) {
      float v = den[mt][r];
      v += __shfl_xor(v, 1, 64); v += __shfl_xor(v, 2, 64);
      v += __shfl_xor(v, 4, 64); v += __shfl_xor(v, 8, 64);
      if (col == 0) sDen[ng][mg * 32 + mt * 16 + quad * 4 + r] = v;
    }
  __syncthreads();

  // epilogue: fused = num/den + itp
#pragma unroll
  for (int mt = 0; mt < 2; mt++)
#pragma unroll
    for (int r = 0; r < 4; r++) {
      int row = mg * 32 + mt * 16 + quad * 4 + r;
      int t = m0 + row;
      float dinv = 1.0f / (sDen[0][row] + sDen[1][row]);
      const u16* ip = itp + ((size_t)(b * TT + t)) * DIM;
      u16* op = fused + ((size_t)(b * TT + t)) * FD + dstoff;
#pragma unroll
      for (int dt = 0; dt < 8; dt++) {
        int d = ng * 128 + dt * 16 + col;
        float val = acc[mt][dt][r] * dinv + bf2f(ip[d]);
        op[d] = f2bf(val);
      }
    }
}

// ---------------- proj: out = gelu(fused @ Wp^T + b), fp32 out -------------
// Double-buffered prefetch (conv-style): stage kt+1 during compute of kt,
// one barrier per step (drains the prefetch that flew under the MFMAs).
__global__ __launch_bounds__(256) void k_proj(const u16* __restrict__ Am,
                                              const u16* __restrict__ Bw,
                                              const float* __restrict__ bias,
                                              float* __restrict__ out) {
  __shared__ __align__(16) u16 As[2][128 * 32], Bs[2][128 * 32];
  int m0 = blockIdx.y * 128, n0 = blockIdx.x * 128;
  int tid = threadIdx.x, wave = tid >> 6, lane = tid & 63;
  int col = lane & 15, quad = lane >> 4;
  int wm = (wave >> 1) * 64, wn = (wave & 1) * 64;
  int lrow = lane >> 2, lcol = (lane & 3) * 8;
  const u16* Ab = Am + (size_t)m0 * FD;
  const u16* Bb = Bw + (size_t)n0 * FD;
  f32x4 acc[4][4];
  f32x4 zz = {0.f, 0.f, 0.f, 0.f};
#pragma unroll
  for (int i = 0; i < 4; i++)
#pragma unroll
    for (int j = 0; j < 4; j++) acc[i][j] = zz;

  auto stage = [&](int kt) {
    int bsel = kt & 1, k0 = kt * 32;
#pragma unroll
    for (int i = 0; i < 2; i++) {
      int rb = wave * 32 + i * 16;
      async16(Ab + ((size_t)(rb + lrow)) * FD + k0 + lcol, &As[bsel][rb * 32]);
      async16(Bb + ((size_t)(rb + lrow)) * FD + k0 + lcol, &Bs[bsel][rb * 32]);
    }
  };

  stage(0);
  __syncthreads();
  for (int kt = 0; kt < 16; kt++) {
    if (kt < 15) stage(kt + 1);
    int bsel = kt & 1;
    bf16x8 af[4], bfr[4];
#pragma unroll
    for (int mt = 0; mt < 4; mt++) af[mt] = *(const bf16x8*)(&As[bsel][0] + (wm + mt * 16 + col) * 32 + quad * 8);
#pragma unroll
    for (int nt = 0; nt < 4; nt++) bfr[nt] = *(const bf16x8*)(&Bs[bsel][0] + (wn + nt * 16 + col) * 32 + quad * 8);
#pragma unroll
    for (int mt = 0; mt < 4; mt++)
#pragma unroll
      for (int nt = 0; nt < 4; nt++)
        acc[mt][nt] = __builtin_amdgcn_mfma_f32_16x16x32_bf16(af[mt], bfr[nt], acc[mt][nt], 0, 0, 0);
    __syncthreads();   // prefetch kt+1 landed; reads of buf[kt&1] done
  }
#pragma unroll
  for (int nt = 0; nt < 4; nt++) {
    float bia = bias[n0 + wn + nt * 16 + col];
#pragma unroll
    for (int mt = 0; mt < 4; mt++)
#pragma unroll
      for (int r = 0; r < 4; r++) {
        int row = m0 + wm + mt * 16 + quad * 4 + r;
        int cc = n0 + wn + nt * 16 + col;
        out[(size_t)row * FD + cc] = gelu_f(acc[mt][nt][r] + bia);
      }
  }
}

extern "C" void kernel_launch(void* const* d_in, const int* in_sizes, int n_in,
                              void* d_out, int out_size, void* d_ws, size_t ws_size,
                              hipStream_t stream) {
  const float* audio = (const float*)d_in[0];
  const float* video = (const float*)d_in[1];
  const float* a3w = (const float*)d_in[2];
  const float* a3b = (const float*)d_in[3];
  const float* a5w = (const float*)d_in[4];
  const float* a5b = (const float*)d_in[5];
  const float* v3w = (const float*)d_in[6];
  const float* v3b = (const float*)d_in[7];
  const float* v5w = (const float*)d_in[8];
  const float* v5b = (const float*)d_in[9];
  const float* pw  = (const float*)d_in[10];
  const float* pb  = (const float*)d_in[11];
  float* out = (float*)d_out;

  char* ws = (char*)d_ws;
  size_t off = 0;
  auto alloc = [&](size_t bytes) {
    char* p = ws + off;
    off += (bytes + 255) & ~(size_t)255;
    return p;
  };
  size_t szItp = (size_t)BATCH * TT * DIM * 2;
  u16* a_itp = (u16*)alloc(szItp);
  u16* v_itp = (u16*)alloc(szItp);
  u16* aM  = (u16*)alloc(szItp);
  u16* vM  = (u16*)alloc(szItp);
  u16* aMT = (u16*)alloc(szItp);
  u16* vMT = (u16*)alloc(szItp);
  // NOTE: naq/nvq must stay adjacent (one zero pass in k_prep covers both;
  // each is 16*1536*4 = 98304 B, a multiple of the 256 B alloc granule).
  float* naq = (float*)alloc((size_t)BATCH * TT * 4);
  float* nvq = (float*)alloc((size_t)BATCH * TT * 4);
  u16* fusedb = (u16*)alloc((size_t)BATCH * TT * FD * 2);
  u16* w3a = (u16*)alloc(3 * 128 * 256 * 2);
  u16* w5a = (u16*)alloc(5 * 128 * 256 * 2);
  u16* w3v = (u16*)alloc(3 * 128 * 256 * 2);
  u16* w5v = (u16*)alloc(5 * 128 * 256 * 2);
  u16* wp  = (u16*)alloc(512 * 512 * 2);

  k_prep<<<3264, 256, 0, stream>>>(a3w, a5w, v3w, v5w, pw, w3a, w5a, w3v, w5v, wp, naq);
  k_interp<<<dim3(192, 16), 256, 0, stream>>>(audio, a_itp, TA, (float)((double)TA / TT));
  k_interp<<<dim3(192, 16), 256, 0, stream>>>(video, v_itp, TV, (float)((double)TV / TT));
  k_convN<3><<<dim3(24, 16, 2), 256, 0, stream>>>(a_itp, v_itp, w3a, w3v, a3b, v3b,
                                                  aM, vM, aMT, vMT, naq, nvq);
  k_convN<5><<<dim3(24, 16, 2), 256, 0, stream>>>(a_itp, v_itp, w5a, w5v, a5b, v5b,
                                                  aM, vM, aMT, vMT, naq, nvq);
  k_flash<<<512, 384, 0, stream>>>(aM, vM, aMT, vMT, naq, nvq, a_itp, v_itp, fusedb);
  k_proj<<<dim3(4, 192), 256, 0, stream>>>(fusedb, wp, pb, out);
}

// Round 10
// 331.062 us; speedup vs baseline: 1.3770x; 1.3770x over previous
//
#include <hip/hip_runtime.h>
#include <math.h>

#define BATCH 16
#define TA 2048
#define TV 1024
#define TT 1536
#define DIM 256
#define FD 512

typedef unsigned short u16;
typedef unsigned int u32;
typedef short bf16x8 __attribute__((ext_vector_type(8)));
typedef float f32x4 __attribute__((ext_vector_type(4)));

__device__ __forceinline__ float bf2f(u16 u) {
  union { u32 i; float f; } v; v.i = ((u32)u) << 16; return v.f;
}
__device__ __forceinline__ u16 f2bf(float f) {
  union { float f; u32 i; } v; v.f = f;
  return (u16)((v.i + 0x7fffu + ((v.i >> 16) & 1u)) >> 16);  // RNE
}
__device__ __forceinline__ float gelu_f(float x) {
  return 0.5f * x * (1.0f + erff(x * 0.70710678118654752440f));
}
// async global->LDS, 16B per lane. LDS dest = wave-uniform base + lane*16.
__device__ __forceinline__ void async16(const u16* g, u16* l) {
  __builtin_amdgcn_global_load_lds((const __attribute__((address_space(1))) void*)g,
                                   (__attribute__((address_space(3))) void*)l, 16, 0, 0);
}

// ---- weight prep: fp32 -> bf16 (+ zeroing the nsq accumulators, fused).
// Conv weights permuted to K-ordered async16-ready chunks:
//   W[kk][unit][8] with kk = tap*8 + c0/32, unit = (o>>4)*64 + q*16 + (o&15),
//   elem j: c = (kk&7)*32 + q*8 + j. Chunk kk = 8 KB contiguous.
__global__ __launch_bounds__(256) void k_prep(
    const float* __restrict__ a3w, const float* __restrict__ a5w,
    const float* __restrict__ v3w, const float* __restrict__ v5w,
    const float* __restrict__ pw,
    u16* __restrict__ w3a, u16* __restrict__ w5a,
    u16* __restrict__ w3v, u16* __restrict__ w5v, u16* __restrict__ wp,
    float* __restrict__ nz) {
  int idx = blockIdx.x * 256 + threadIdx.x;
  if (idx < 524288) {
    int e, ktaps;
    const float* src;
    u16* dst;
    if (idx < 98304)       { e = idx;          ktaps = 3; src = a3w; dst = w3a; }
    else if (idx < 262144) { e = idx - 98304;  ktaps = 5; src = a5w; dst = w5a; }
    else if (idx < 360448) { e = idx - 262144; ktaps = 3; src = v3w; dst = w3v; }
    else                   { e = idx - 360448; ktaps = 5; src = v5w; dst = w5v; }
    int kk = e >> 12, r = e & 4095;
    int j = r & 7, unit = r >> 3;
    int fb = unit >> 6, rem = unit & 63;
    int q = rem >> 4, colp = rem & 15;
    int o = fb * 16 + colp;
    int tap = kk >> 3;
    int c = (kk & 7) * 32 + q * 8 + j;
    dst[e] = f2bf(src[(o * 256 + c) * ktaps + tap]);
  } else if (idx < 786432) {               // proj [512][512] straight copy
    int t = idx - 524288;
    wp[t] = f2bf(pw[t]);
  } else if (idx < 835584) {               // zero naq/nvq (adjacent, 49152 f32)
    nz[idx - 786432] = 0.f;
  }
}

// ------- linear interp to T=1536, both directions in one launch -----------
// grid (192, 16, 2): z=0 audio (t_in=TA), z=1 video (t_in=TV).
__global__ __launch_bounds__(256) void k_interp2(const float* __restrict__ a_in,
                                                 const float* __restrict__ v_in,
                                                 u16* __restrict__ a_out,
                                                 u16* __restrict__ v_out) {
  int z = blockIdx.z;
  const float* in = z ? v_in : a_in;
  u16* out = z ? v_out : a_out;
  int t_in = z ? TV : TA;
  float scale = z ? (float)((double)TV / TT) : (float)((double)TA / TT);
  int b = blockIdx.y;
  int i = blockIdx.x * 256 + threadIdx.x;   // [0, TT*32)
  int t = i >> 5, dg = i & 31;              // dg: group of 8 dims
  float src = ((float)t + 0.5f) * scale - 0.5f;
  src = fmaxf(src, 0.0f);
  int i0 = (int)floorf(src);
  if (i0 > t_in - 1) i0 = t_in - 1;
  int i1 = i0 + 1; if (i1 > t_in - 1) i1 = t_in - 1;
  float w = src - (float)i0;
  float om = 1.0f - w;
  const float4* p0 = (const float4*)(in + ((size_t)(b * t_in + i0)) * DIM + dg * 8);
  const float4* p1 = (const float4*)(in + ((size_t)(b * t_in + i1)) * DIM + dg * 8);
  float4 x0a = p0[0], x0b = p0[1], x1a = p1[0], x1b = p1[1];
  u16 r[8];
  r[0] = f2bf(x0a.x * om + x1a.x * w); r[1] = f2bf(x0a.y * om + x1a.y * w);
  r[2] = f2bf(x0a.z * om + x1a.z * w); r[3] = f2bf(x0a.w * om + x1a.w * w);
  r[4] = f2bf(x0b.x * om + x1b.x * w); r[5] = f2bf(x0b.y * om + x1b.y * w);
  r[6] = f2bf(x0b.z * om + x1b.z * w); r[7] = f2bf(x0b.w * om + x1b.w * w);
  u32 w0 = (u32)r[0] | ((u32)r[1] << 16), w1 = (u32)r[2] | ((u32)r[3] << 16);
  u32 w2 = (u32)r[4] | ((u32)r[5] << 16), w3 = (u32)r[6] | ((u32)r[7] << 16);
  *(uint4*)(out + ((size_t)(b * TT + t)) * DIM + dg * 8) = make_uint4(w0, w1, w2, w3);
}

// ---------------- conv GEMM body (shared by taps=3/5, one launch) ----------
// TAPS=3 -> output channels [0,128), TAPS=5 -> [128,256).
// Per block: 64 t-rows x 128 channels. isv selects audio/video.
// Wave w owns channels [w*32, w*32+32) for all 64 rows.
// nsq accumulated atomically (pre-zeroed). xs/Bs passed from the kernel so
// both template instantiations share ONE LDS allocation (44 KB, 3 blocks/CU).
template <int TAPS>
__device__ __forceinline__ void conv_body(
    int isv, u16* xs, u16* Bs,
    const u16* __restrict__ xa, const u16* __restrict__ xv,
    const u16* __restrict__ Wa, const u16* __restrict__ Wv,
    const float* __restrict__ ba, const float* __restrict__ bv,
    u16* __restrict__ outMa, u16* __restrict__ outMv,
    u16* __restrict__ outTa, u16* __restrict__ outTv,
    float* __restrict__ nsqa, float* __restrict__ nsqv) {
  constexpr int S = TAPS * 8;
  constexpr int OFF = (TAPS == 3) ? 1 : 2;
  constexpr int CHB = (TAPS == 3) ? 0 : 128;
  u16* tb = xs;                                // [128][72] transpose buffer (epilogue)
  int b = blockIdx.y, t0 = blockIdx.x * 64;
  const u16* xin = isv ? xv : xa;
  const u16* W   = isv ? Wv : Wa;
  const float* bias = isv ? bv : ba;
  u16* outM  = isv ? outMv : outMa;
  u16* outT  = isv ? outTv : outTa;
  float* nsq = isv ? nsqv : nsqa;
  int tid = threadIdx.x, wave = tid >> 6, lane = tid & 63;
  int col = lane & 15, quad = lane >> 4;

  // stage 68 input rows (zeros outside [0,T))
  for (int i = tid; i < 68 * 32; i += 256) {
    int row = i >> 5, un = i & 31;
    int t = t0 + row - 2;
    uint4 val = make_uint4(0, 0, 0, 0);
    if (t >= 0 && t < TT) val = *(const uint4*)(xin + ((size_t)(b * TT + t)) * DIM + un * 8);
    *(uint4*)(xs + row * 264 + un * 8) = val;
  }
  // prefetch chunk 0 into buf 0 (each wave stages 1024 elems = 2 x 16B/lane)
  const u16* Wb = W + wave * 1024 + lane * 8;
  u16* BsW = Bs + wave * 1024;
  async16(Wb, BsW);
  async16(Wb + 512, BsW + 512);

  f32x4 acc[4][2];
  f32x4 zz = {0.f, 0.f, 0.f, 0.f};
#pragma unroll
  for (int rt = 0; rt < 4; rt++) { acc[rt][0] = zz; acc[rt][1] = zz; }

  const u16* afp = xs + (col + 2) * 264 + quad * 8;
  const u16* bfp = Bs + wave * 1024 + quad * 128 + col * 8;

#pragma unroll
  for (int s = 0; s < S; s++) {
    __syncthreads();                 // chunk s staged; prev reads of other buf done
    if (s + 1 < S) {
      const u16* src = Wb + (size_t)(s + 1) * 4096;
      u16* dst = Bs + ((s + 1) & 1) * 4096 + wave * 1024;
      async16(src, dst);
      async16(src + 512, dst + 512);
    }
    int shift = (s >> 3) - OFF;      // compile-time after unroll
    int c0 = (s & 7) * 32;
    bf16x8 af[4];
#pragma unroll
    for (int rt = 0; rt < 4; rt++)
      af[rt] = *(const bf16x8*)(afp + (rt * 16 + shift) * 264 + c0);
    bf16x8 bf0 = *(const bf16x8*)(bfp + (s & 1) * 4096);
    bf16x8 bf1 = *(const bf16x8*)(bfp + (s & 1) * 4096 + 512);
#pragma unroll
    for (int rt = 0; rt < 4; rt++) {
      acc[rt][0] = __builtin_amdgcn_mfma_f32_16x16x32_bf16(af[rt], bf0, acc[rt][0], 0, 0, 0);
      acc[rt][1] = __builtin_amdgcn_mfma_f32_16x16x32_bf16(af[rt], bf1, acc[rt][1], 0, 0, 0);
    }
  }
  __syncthreads();                   // xs reads done; safe to overlay tb

  // epilogue: bias + gelu + per-row sumsq (32 ch of this wave) + tb + outM
  float bia0 = bias[wave * 32 + col];
  float bia1 = bias[wave * 32 + 16 + col];
  float ss[4][4];
#pragma unroll
  for (int rt = 0; rt < 4; rt++)
#pragma unroll
    for (int r = 0; r < 4; r++) ss[rt][r] = 0.f;
#pragma unroll
  for (int rt = 0; rt < 4; rt++)
#pragma unroll
    for (int h = 0; h < 2; h++) {
      float bia = h ? bia1 : bia0;
      int chL = wave * 32 + h * 16 + col;
#pragma unroll
      for (int r = 0; r < 4; r++) {
        float g = gelu_f(acc[rt][h][r] + bia);
        ss[rt][r] += g * g;
        int trow = rt * 16 + quad * 4 + r;
        u16 gb = f2bf(g);
        tb[chL * 72 + trow] = gb;
        outM[((size_t)(b * TT + t0 + trow)) * DIM + CHB + chL] = gb;
      }
    }
#pragma unroll
  for (int rt = 0; rt < 4; rt++)
#pragma unroll
    for (int r = 0; r < 4; r++) {
      float v = ss[rt][r];
      v += __shfl_xor(v, 1, 64); v += __shfl_xor(v, 2, 64);
      v += __shfl_xor(v, 4, 64); v += __shfl_xor(v, 8, 64);
      if (col == 0)
        atomicAdd(&nsq[b * TT + t0 + rt * 16 + quad * 4 + r], v);
    }
  __syncthreads();
  // outT: 2 threads per channel write 32 contiguous t each
  {
    int ch = tid >> 1, half = tid & 1;
    uint4* dst = (uint4*)(outT + ((size_t)(b * 256 + CHB + ch)) * TT + t0 + half * 32);
#pragma unroll
    for (int i = 0; i < 4; i++)
      dst[i] = *(const uint4*)(tb + ch * 72 + half * 32 + i * 8);
  }
}

// one launch for all 4 conv variants: grid (24,16,4); z&1 = a/v, z>>1 = taps.
__global__ __launch_bounds__(256) void k_conv(
    const u16* __restrict__ xa, const u16* __restrict__ xv,
    const u16* __restrict__ W3a, const u16* __restrict__ W3v,
    const u16* __restrict__ W5a, const u16* __restrict__ W5v,
    const float* __restrict__ b3a, const float* __restrict__ b3v,
    const float* __restrict__ b5a, const float* __restrict__ b5v,
    u16* __restrict__ outMa, u16* __restrict__ outMv,
    u16* __restrict__ outTa, u16* __restrict__ outTv,
    float* __restrict__ nsqa, float* __restrict__ nsqv) {
  __shared__ __align__(16) u16 xs[68 * 264];   // input rows; tb overlays
  __shared__ __align__(16) u16 Bs[2 * 4096];   // weight chunk double buffer
  int z = blockIdx.z;
  if (z < 2)
    conv_body<3>(z, xs, Bs, xa, xv, W3a, W3v, b3a, b3v,
                 outMa, outMv, outTa, outTv, nsqa, nsqv);
  else
    conv_body<5>(z - 2, xs, Bs, xa, xv, W5a, W5v, b5a, b5v,
                 outMa, outMv, outTa, outTv, nsqa, nsqv);
}

// ---- fused flash cross-attention (r8-verified: r1 structure + staggered
// single-buffer pipeline). 768 blocks, 256 thr (4 waves, mg/ng 2x2),
// 64 Q-rows/block, 24 KV-steps of 64 rows, LDS 72.5 KB -> exactly 2
// blocks/CU (even packing keeps group lockstep -> L2 serves panel reads).
// Per step (counted-vmcnt stagger, sim only reads sKV / PV only reads sKT):
//   P1 sim+exp            B1 vmcnt(0)+lgkm+bar  (sKT(t) lands under sim)
//   P2 issue sKV(t+1), PV B2 lgkm+bar
//   P3 issue sKT(t+1)     W  vmcnt(8)+bar       (sKV(t+1) lands; 8 sKT fly on)
// E = exp(cossim*sRa*sRv) bounded => no running max.
// r7 ERRATA: packed cvt_pk E-stores = bank conflicts; keep scalar epilogue.
// r9 ERRATA: LDS > ~74 KB drops to 1 block/CU (78.8 KB ran solo, 2x slower);
// the 96-row no-tail tile (78.6 KB floor) is infeasible — keep 64-row/72.5 KB.
__global__ __launch_bounds__(256, 2) void k_flash(
    const u16* __restrict__ aM, const u16* __restrict__ vM,
    const u16* __restrict__ aMT, const u16* __restrict__ vMT,
    const float* __restrict__ naq, const float* __restrict__ nvq,
    const u16* __restrict__ a_itp, const u16* __restrict__ v_itp,
    u16* __restrict__ fused) {
  __shared__ __align__(16) u16 sKV[8 * 64 * 32];    // sim B  [kt][64][32]
  __shared__ __align__(16) u16 sKT[2 * 256 * 32];   // PV  B  [kn][256][32]
  __shared__ __align__(16) u16 sE[2 * 32 * 64];     // E      [mg][32][64]
  __shared__ float sDen[2][64];

  // XCD-chunked decode: blocks sharing one (b,z) KV panel land on one XCD L2.
  int wgid = blockIdx.x;                 // [0, 768)
  int xcd = wgid & 7, j = wgid >> 3;     // j in [0,96)
  int g = xcd + 8 * (j / 24);            // group (b,z) in [0,32)
  int m0 = (j % 24) * 64;
  int b = g & 15, z = g >> 4;
  const u16* Q    = z ? vM : aM;
  const u16* KV   = z ? aM : vM;
  const u16* KVT  = z ? aMT : vMT;
  const float* nq = z ? nvq : naq;
  const float* nk = z ? naq : nvq;
  const u16* itp  = z ? v_itp : a_itp;
  int dstoff = z ? 256 : 0;

  int tid = threadIdx.x, w = tid >> 6, lane = tid & 63;
  int mg = w >> 1, ng = w & 1;
  int col = lane & 15, quad = lane >> 4;
  int li = lane >> 2;                       // staging row within 16
  int sq = (lane & 3) ^ ((lane >> 3) & 3);  // pre-swizzled global k-slot

  const u16* KVb = KV + ((size_t)b * TT) * DIM;
  const u16* KTb = KVT + ((size_t)b * 256) * TT;
  const float* nkB = nk + (size_t)b * TT;

  // per-wave staging: 8 sKV units + 8 sKT units (16B/lane each)
  auto stageKV = [&](int n0s) {
#pragma unroll
    for (int kk = 0; kk < 2; kk++) {
      int kt = w * 2 + kk;
#pragma unroll
      for (int i = 0; i < 4; i++)
        async16(KVb + (size_t)(n0s + i * 16 + li) * DIM + kt * 32 + sq * 8,
                sKV + kt * 2048 + i * 512);
    }
  };
  auto stageKT = [&](int n0s) {
#pragma unroll
    for (int kn = 0; kn < 2; kn++)
#pragma unroll
      for (int i = 0; i < 4; i++)
        async16(KTb + (size_t)(w * 64 + i * 16 + li) * TT + n0s + kn * 32 + sq * 8,
                sKT + kn * 8192 + w * 2048 + i * 512);
  };

  // Q fragments in registers: rows m0+mg*32+mt*16+col, k = kt*32+quad*8
  bf16x8 qf[2][8];
  const u16* Qb = Q + ((size_t)(b * TT + m0 + mg * 32)) * DIM;
#pragma unroll
  for (int mt = 0; mt < 2; mt++)
#pragma unroll
    for (int kt = 0; kt < 8; kt++)
      qf[mt][kt] = *(const bf16x8*)(Qb + (size_t)(mt * 16 + col) * DIM + kt * 32 + quad * 8);

  // inverse norms for this lane's 8 accumulator rows
  float sra[2][4];
#pragma unroll
  for (int mt = 0; mt < 2; mt++)
#pragma unroll
    for (int r = 0; r < 4; r++)
      sra[mt][r] = 1.0f / fmaxf(
          sqrtf(nq[(size_t)b * TT + m0 + mg * 32 + mt * 16 + quad * 4 + r]), 1e-12f);

  // per-lane K-norm columns (2 per step), step-0 raw values
  int c0 = ng * 32 + col, c1 = ng * 32 + 16 + col;
  float rvRaw0 = nkB[c0], rvRaw1 = nkB[c1];

  f32x4 acc[2][8];                       // PV accumulators [mt][dt]
  f32x4 zz = {0.f, 0.f, 0.f, 0.f};
#pragma unroll
  for (int mt = 0; mt < 2; mt++)
#pragma unroll
    for (int dt = 0; dt < 8; dt++) acc[mt][dt] = zz;
  float den[2][4];
#pragma unroll
  for (int mt = 0; mt < 2; mt++)
#pragma unroll
    for (int r = 0; r < 4; r++) den[mt][r] = 0.f;

  // prologue: stage step 0 fully, drain
  stageKV(0);
  stageKT(0);
  __syncthreads();

  for (int t = 0; t < 24; t++) {
    int n0 = t * 64;
    // ---- P1: sim (reads sKV only) + exp/sE
    f32x4 sc[2][2];
    sc[0][0] = zz; sc[0][1] = zz; sc[1][0] = zz; sc[1][1] = zz;
#pragma unroll
    for (int kt = 0; kt < 8; kt++)
#pragma unroll
      for (int nt = 0; nt < 2; nt++) {
        int row = ng * 32 + nt * 16 + col;
        bf16x8 bf = *(const bf16x8*)(sKV + kt * 2048 + row * 32 +
                                     ((quad ^ ((row >> 1) & 3)) << 3));
        sc[0][nt] = __builtin_amdgcn_mfma_f32_16x16x32_bf16(qf[0][kt], bf, sc[0][nt], 0, 0, 0);
        sc[1][nt] = __builtin_amdgcn_mfma_f32_16x16x32_bf16(qf[1][kt], bf, sc[1][nt], 0, 0, 0);
      }
    float rvi[2];
    rvi[0] = 1.0f / fmaxf(sqrtf(rvRaw0), 1e-12f);
    rvi[1] = 1.0f / fmaxf(sqrtf(rvRaw1), 1e-12f);
#pragma unroll
    for (int mt = 0; mt < 2; mt++)
#pragma unroll
      for (int nt = 0; nt < 2; nt++) {
        int c = ng * 32 + nt * 16 + col;
        float rv = rvi[nt];
#pragma unroll
        for (int r = 0; r < 4; r++) {
          float e = __expf(sc[mt][nt][r] * sra[mt][r] * rv);
          den[mt][r] += e;
          int row = mt * 16 + quad * 4 + r;
          sE[mg * 2048 + row * 64 + (((c >> 3) ^ ((row >> 1) & 7)) << 3) + (c & 7)] =
              f2bf(e);
        }
      }

    // ---- B1: sKT(t) landed + sE visible + all sKV reads done
    __builtin_amdgcn_sched_barrier(0);
    asm volatile("s_waitcnt vmcnt(0) lgkmcnt(0)" ::: "memory");
    __builtin_amdgcn_s_barrier();
    __builtin_amdgcn_sched_barrier(0);

    // ---- P2: issue next-step rv loads + sKV(t+1); then PV (reads sE, sKT)
    int nn = (t < 23) ? (n0 + 64) : 0;
    float rvA = nkB[nn + c0], rvB = nkB[nn + c1];
    if (t < 23) stageKV(n0 + 64);
#pragma unroll
    for (int kn = 0; kn < 2; kn++) {
      bf16x8 ea0, ea1;
      {
        int row = col;                   // mt = 0
        ea0 = *(const bf16x8*)(sE + mg * 2048 + row * 64 +
                               (((kn * 4 + quad) ^ ((row >> 1) & 7)) << 3));
        row = 16 + col;                  // mt = 1
        ea1 = *(const bf16x8*)(sE + mg * 2048 + row * 64 +
                               (((kn * 4 + quad) ^ ((row >> 1) & 7)) << 3));
      }
#pragma unroll
      for (int dt = 0; dt < 8; dt++) {
        int drow = ng * 128 + dt * 16 + col;
        bf16x8 bf = *(const bf16x8*)(sKT + kn * 8192 + drow * 32 +
                                     ((quad ^ ((drow >> 1) & 3)) << 3));
        acc[0][dt] = __builtin_amdgcn_mfma_f32_16x16x32_bf16(ea0, bf, acc[0][dt], 0, 0, 0);
        acc[1][dt] = __builtin_amdgcn_mfma_f32_16x16x32_bf16(ea1, bf, acc[1][dt], 0, 0, 0);
      }
    }

    // ---- B2: all sKT(t)/sE reads done
    __builtin_amdgcn_sched_barrier(0);
    asm volatile("s_waitcnt lgkmcnt(0)" ::: "memory");
    __builtin_amdgcn_s_barrier();
    __builtin_amdgcn_sched_barrier(0);

    // ---- P3: issue sKT(t+1); W: wait sKV(t+1) only (8 sKT stay in flight)
    if (t < 23) stageKT(n0 + 64);
    __builtin_amdgcn_sched_barrier(0);
    asm volatile("s_waitcnt vmcnt(8) lgkmcnt(0)" ::: "memory");
    __builtin_amdgcn_s_barrier();
    __builtin_amdgcn_sched_barrier(0);

    rvRaw0 = rvA; rvRaw1 = rvB;
  }

  // den: butterfly over 16 cols, then combine the two ng waves via LDS
#pragma unroll
  for (int mt = 0; mt < 2; mt++)
#pragma unroll
    for (int r = 0; r < 4; r++) {
      float v = den[mt][r];
      v += __shfl_xor(v, 1, 64); v += __shfl_xor(v, 2, 64);
      v += __shfl_xor(v, 4, 64); v += __shfl_xor(v, 8, 64);
      if (col == 0) sDen[ng][mg * 32 + mt * 16 + quad * 4 + r] = v;
    }
  __syncthreads();

  // epilogue: fused = num/den + itp
#pragma unroll
  for (int mt = 0; mt < 2; mt++)
#pragma unroll
    for (int r = 0; r < 4; r++) {
      int row = mg * 32 + mt * 16 + quad * 4 + r;
      int t = m0 + row;
      float dinv = 1.0f / (sDen[0][row] + sDen[1][row]);
      const u16* ip = itp + ((size_t)(b * TT + t)) * DIM;
      u16* op = fused + ((size_t)(b * TT + t)) * FD + dstoff;
#pragma unroll
      for (int dt = 0; dt < 8; dt++) {
        int d = ng * 128 + dt * 16 + col;
        float val = acc[mt][dt][r] * dinv + bf2f(ip[d]);
        op[d] = f2bf(val);
      }
    }
}

// ---------------- proj: out = gelu(fused @ Wp^T + b), fp32 out -------------
// Double-buffered prefetch (conv-style): stage kt+1 during compute of kt,
// one barrier per step (drains the prefetch that flew under the MFMAs).
__global__ __launch_bounds__(256) void k_proj(const u16* __restrict__ Am,
                                              const u16* __restrict__ Bw,
                                              const float* __restrict__ bias,
                                              float* __restrict__ out) {
  __shared__ __align__(16) u16 As[2][128 * 32], Bs[2][128 * 32];
  int m0 = blockIdx.y * 128, n0 = blockIdx.x * 128;
  int tid = threadIdx.x, wave = tid >> 6, lane = tid & 63;
  int col = lane & 15, quad = lane >> 4;
  int wm = (wave >> 1) * 64, wn = (wave & 1) * 64;
  int lrow = lane >> 2, lcol = (lane & 3) * 8;
  const u16* Ab = Am + (size_t)m0 * FD;
  const u16* Bb = Bw + (size_t)n0 * FD;
  f32x4 acc[4][4];
  f32x4 zz = {0.f, 0.f, 0.f, 0.f};
#pragma unroll
  for (int i = 0; i < 4; i++)
#pragma unroll
    for (int j = 0; j < 4; j++) acc[i][j] = zz;

  auto stage = [&](int kt) {
    int bsel = kt & 1, k0 = kt * 32;
#pragma unroll
    for (int i = 0; i < 2; i++) {
      int rb = wave * 32 + i * 16;
      async16(Ab + ((size_t)(rb + lrow)) * FD + k0 + lcol, &As[bsel][rb * 32]);
      async16(Bb + ((size_t)(rb + lrow)) * FD + k0 + lcol, &Bs[bsel][rb * 32]);
    }
  };

  stage(0);
  __syncthreads();
  for (int kt = 0; kt < 16; kt++) {
    if (kt < 15) stage(kt + 1);
    int bsel = kt & 1;
    bf16x8 af[4], bfr[4];
#pragma unroll
    for (int mt = 0; mt < 4; mt++) af[mt] = *(const bf16x8*)(&As[bsel][0] + (wm + mt * 16 + col) * 32 + quad * 8);
#pragma unroll
    for (int nt = 0; nt < 4; nt++) bfr[nt] = *(const bf16x8*)(&Bs[bsel][0] + (wn + nt * 16 + col) * 32 + quad * 8);
#pragma unroll
    for (int mt = 0; mt < 4; mt++)
#pragma unroll
      for (int nt = 0; nt < 4; nt++)
        acc[mt][nt] = __builtin_amdgcn_mfma_f32_16x16x32_bf16(af[mt], bfr[nt], acc[mt][nt], 0, 0, 0);
    __syncthreads();   // prefetch kt+1 landed; reads of buf[kt&1] done
  }
#pragma unroll
  for (int nt = 0; nt < 4; nt++) {
    float bia = bias[n0 + wn + nt * 16 + col];
#pragma unroll
    for (int mt = 0; mt < 4; mt++)
#pragma unroll
      for (int r = 0; r < 4; r++) {
        int row = m0 + wm + mt * 16 + quad * 4 + r;
        int cc = n0 + wn + nt * 16 + col;
        out[(size_t)row * FD + cc] = gelu_f(acc[mt][nt][r] + bia);
      }
  }
}

extern "C" void kernel_launch(void* const* d_in, const int* in_sizes, int n_in,
                              void* d_out, int out_size, void* d_ws, size_t ws_size,
                              hipStream_t stream) {
  const float* audio = (const float*)d_in[0];
  const float* video = (const float*)d_in[1];
  const float* a3w = (const float*)d_in[2];
  const float* a3b = (const float*)d_in[3];
  const float* a5w = (const float*)d_in[4];
  const float* a5b = (const float*)d_in[5];
  const float* v3w = (const float*)d_in[6];
  const float* v3b = (const float*)d_in[7];
  const float* v5w = (const float*)d_in[8];
  const float* v5b = (const float*)d_in[9];
  const float* pw  = (const float*)d_in[10];
  const float* pb  = (const float*)d_in[11];
  float* out = (float*)d_out;

  char* ws = (char*)d_ws;
  size_t off = 0;
  auto alloc = [&](size_t bytes) {
    char* p = ws + off;
    off += (bytes + 255) & ~(size_t)255;
    return p;
  };
  size_t szItp = (size_t)BATCH * TT * DIM * 2;
  u16* a_itp = (u16*)alloc(szItp);
  u16* v_itp = (u16*)alloc(szItp);
  u16* aM  = (u16*)alloc(szItp);
  u16* vM  = (u16*)alloc(szItp);
  u16* aMT = (u16*)alloc(szItp);
  u16* vMT = (u16*)alloc(szItp);
  // NOTE: naq/nvq must stay adjacent (one zero pass in k_prep covers both;
  // each is 16*1536*4 = 98304 B, a multiple of the 256 B alloc granule).
  float* naq = (float*)alloc((size_t)BATCH * TT * 4);
  float* nvq = (float*)alloc((size_t)BATCH * TT * 4);
  u16* fusedb = (u16*)alloc((size_t)BATCH * TT * FD * 2);
  u16* w3a = (u16*)alloc(3 * 128 * 256 * 2);
  u16* w5a = (u16*)alloc(5 * 128 * 256 * 2);
  u16* w3v = (u16*)alloc(3 * 128 * 256 * 2);
  u16* w5v = (u16*)alloc(5 * 128 * 256 * 2);
  u16* wp  = (u16*)alloc(512 * 512 * 2);

  k_prep<<<3264, 256, 0, stream>>>(a3w, a5w, v3w, v5w, pw, w3a, w5a, w3v, w5v, wp, naq);
  k_interp2<<<dim3(192, 16, 2), 256, 0, stream>>>(audio, video, a_itp, v_itp);
  k_conv<<<dim3(24, 16, 4), 256, 0, stream>>>(a_itp, v_itp, w3a, w3v, w5a, w5v,
                                              a3b, v3b, a5b, v5b,
                                              aM, vM, aMT, vMT, naq, nvq);
  k_flash<<<768, 256, 0, stream>>>(aM, vM, aMT, vMT, naq, nvq, a_itp, v_itp, fusedb);
  k_proj<<<dim3(4, 192), 256, 0, stream>>>(fusedb, wp, pb, out);
}